// Round 12
// baseline (126.461 us; speedup 1.0000x reference)
//
#include <hip/hip_runtime.h>
#include <hip/hip_bf16.h>

// Bilinear edge scoring:  out[e] = x_source[src[e]] @ W @ x_target[tgt[e]] + b
// Factored: Z = x_source @ W via f16 MFMA GEMM (fp32 accum), int8-quantized
//           per-row in the epilogue -> Zq + zscale; Xq = per-row int8 quant
//           of x_target; out[e] = zs[s]*xs[t]*idot(Zq[s], Xq[t]) + b.
// Edge phase (r11): 8 lanes/edge, 16 B/lane -> 8 row-segments per load
// instruction, U=4 batch; runs at 3.37 TB/s = 94% of the measured ~3.6 TB/s
// L2-miss-path wall. This round fuses GEMM + x-quant into one kernel
// (block-role split) so the streaming quant fills GEMM barrier/compute gaps.
// Error: absmax 0.375 measured (threshold 0.69).

#define D 128
#define U 4      // edges per sub-group per wave-iteration (32 edges/wave-iter)

typedef _Float16 f16x8 __attribute__((ext_vector_type(8)));  // 4 VGPR
typedef float f32x4 __attribute__((ext_vector_type(4)));
typedef unsigned int uint;

__device__ __forceinline__ unsigned short f2h(float f) {
    _Float16 h = (_Float16)f;               // RNE
    return *(unsigned short*)&h;
}
__device__ __forceinline__ uint pack2h(float a, float b) {
    return (uint)f2h(a) | ((uint)f2h(b) << 16);
}

__device__ __forceinline__ int dot4x4_i8(uint4 a, uint4 b, int acc) {
#if __has_builtin(__builtin_amdgcn_sdot4)
    acc = __builtin_amdgcn_sdot4((int)a.x, (int)b.x, acc, false);
    acc = __builtin_amdgcn_sdot4((int)a.y, (int)b.y, acc, false);
    acc = __builtin_amdgcn_sdot4((int)a.z, (int)b.z, acc, false);
    acc = __builtin_amdgcn_sdot4((int)a.w, (int)b.w, acc, false);
#else
#pragma unroll
    for (int d = 0; d < 4; ++d) {
        uint av = (&a.x)[d], bv = (&b.x)[d];
#pragma unroll
        for (int k = 0; k < 4; ++k) {
            int az = (int)(signed char)((av >> (8 * k)) & 0xff);
            int bz = (int)(signed char)((bv >> (8 * k)) & 0xff);
            acc += az * bz;
        }
    }
#endif
    return acc;
}

// ---------------------------------------------------------------------------
// Wth[n][k] = fp16(W[k][n])   (one-time 128x128 transpose+cast)
// ---------------------------------------------------------------------------
__global__ __launch_bounds__(256) void wt_cast(const float* __restrict__ W,
                                               unsigned short* __restrict__ Wth) {
    int idx = blockIdx.x * 256 + threadIdx.x;
    int k = idx >> 7, n = idx & 127;
    Wth[n * 128 + k] = f2h(W[idx]);
}

// ---------------------------------------------------------------------------
// Fused prep: blocks [0,ngemm) compute Zq = int8_rowquant(X @ W) via
// mfma_f32_16x16x32_f16 (GEMM verified r8-r11); blocks [ngemm,..) int8-quant
// x_target 64 rows/block (streaming, fills BW gaps during GEMM phases).
// ---------------------------------------------------------------------------
__global__ __launch_bounds__(256) void fused_prep(const float* __restrict__ X,
                                                  const float* __restrict__ XT,
                                                  const unsigned short* __restrict__ Wth,
                                                  signed char* __restrict__ Zq,
                                                  float* __restrict__ zscales,
                                                  signed char* __restrict__ Xq,
                                                  float* __restrict__ xscales,
                                                  int N, int ngemm) {
    __shared__ unsigned short wls[128 * 128];
    __shared__ unsigned short xls[64 * 128];

    const int tid = threadIdx.x;

    if ((int)blockIdx.x >= ngemm) {
        // ---- quant role: 64 rows of x_target per block, wave w -> 16 rows
        const int qb = (int)blockIdx.x - ngemm;
        const int w = tid >> 6;
        const int lane = tid & 63;
        for (int i = 0; i < 16; ++i) {
            const int row = qb * 64 + w * 16 + i;
            if (row >= N) break;
            float2 v = ((const float2*)(XT + (size_t)row * D))[lane];
            float m = fmaxf(fabsf(v.x), fabsf(v.y));
#pragma unroll
            for (int o = 1; o < 64; o <<= 1) m = fmaxf(m, __shfl_xor(m, o, 64));
            const float inv = (m > 0.f) ? 127.0f / m : 0.f;
            const int qa = (int)rintf(v.x * inv);
            const int qc = (int)rintf(v.y * inv);
            unsigned short pk = (unsigned short)(qa & 0xff) |
                                ((unsigned short)(qc & 0xff) << 8);
            *(unsigned short*)((unsigned char*)Xq + (size_t)row * 128 + 2 * lane) = pk;
            if (lane == 0) xscales[row] = (m > 0.f) ? m * (1.0f / 127.0f) : 0.f;
        }
        return;
    }

    // ---- GEMM role (identical to verified r8-r11 kernel)
    const int block_row = blockIdx.x * 64;

#pragma unroll
    for (int j = 0; j < 8; ++j) {
        int c16 = j * 256 + tid;
        int row = c16 >> 4;
        int kb = (c16 & 15) << 4;
        uint4 v = ((const uint4*)Wth)[c16];
        *(uint4*)((char*)wls + row * 256 + (kb ^ ((row & 7) << 4))) = v;
    }
#pragma unroll
    for (int j = 0; j < 4; ++j) {
        int c16 = j * 256 + tid;
        int row = c16 >> 4;
        int kb = (c16 & 15) << 4;
        int grow = block_row + row;
        float4 f0 = make_float4(0.f, 0.f, 0.f, 0.f), f1 = f0;
        if (grow < N) {
            const float4* src = (const float4*)(X + (size_t)grow * D + (kb >> 1));
            f0 = src[0];
            f1 = src[1];
        }
        uint4 v;
        v.x = pack2h(f0.x, f0.y);
        v.y = pack2h(f0.z, f0.w);
        v.z = pack2h(f1.x, f1.y);
        v.w = pack2h(f1.z, f1.w);
        *(uint4*)((char*)xls + row * 256 + (kb ^ ((row & 7) << 4))) = v;
    }
    __syncthreads();

    const int lane = tid & 63;
    const int w = tid >> 6;
    const int lr = lane & 15;
    const int kg = lane >> 4;

    f32x4 acc[8];
#pragma unroll
    for (int nb = 0; nb < 8; ++nb) acc[nb] = (f32x4){0.f, 0.f, 0.f, 0.f};

    const int arow = w * 16 + lr;
    const int swz = (lr & 7) << 4;
#pragma unroll
    for (int ks = 0; ks < 4; ++ks) {
        int kbyte = ks * 64 + kg * 16;
        f16x8 a = *(const f16x8*)((const char*)xls + arow * 256 + (kbyte ^ swz));
#pragma unroll
        for (int nb = 0; nb < 8; ++nb) {
            int nrow = nb * 16 + lr;
            f16x8 b = *(const f16x8*)((const char*)wls + nrow * 256 + (kbyte ^ swz));
            acc[nb] = __builtin_amdgcn_mfma_f32_16x16x32_f16(a, b, acc[nb], 0, 0, 0);
        }
    }

    const int orow0 = block_row + w * 16 + kg * 4;
#pragma unroll
    for (int j = 0; j < 4; ++j) {
        float m = 0.f;
#pragma unroll
        for (int nb = 0; nb < 8; ++nb) m = fmaxf(m, fabsf(acc[nb][j]));
        m = fmaxf(m, __shfl_xor(m, 1, 64));
        m = fmaxf(m, __shfl_xor(m, 2, 64));
        m = fmaxf(m, __shfl_xor(m, 4, 64));
        m = fmaxf(m, __shfl_xor(m, 8, 64));   // max across the 16-lane lr group
        int grow = orow0 + j;
        if (grow < N) {
            float inv = (m > 0.f) ? 127.0f / m : 0.f;
#pragma unroll
            for (int nb = 0; nb < 8; ++nb) {
                int q = (int)rintf(acc[nb][j] * inv);
                Zq[(size_t)grow * 128 + nb * 16 + lr] = (signed char)q;
            }
            if (lr == 0) zscales[grow] = (m > 0.f) ? m * (1.0f / 127.0f) : 0.f;
        }
    }
}

// ---------------------------------------------------------------------------
// Edge pass (verified r11): 8 lanes/edge (lane l -> bytes 16l..16l+15),
// 8 rows = 8 x 128 B segments per load instruction, U=4 -> 32 edges/wave-iter,
// all 8 gather instrs issued before arithmetic. sdot4 dot, 3x shfl_xor
// reduce, scale-product epilogue on lane 0.
// ---------------------------------------------------------------------------
__global__ __launch_bounds__(256) void edge_score_q8(const signed char* __restrict__ Zq,
                                                     const signed char* __restrict__ Xq,
                                                     const float* __restrict__ zscales,
                                                     const float* __restrict__ xscales,
                                                     const int* __restrict__ idx,
                                                     const float* __restrict__ bptr,
                                                     float* __restrict__ out, int E) {
    const float b = bptr[0];
    const int lane = threadIdx.x & 63;
    const int sub = lane >> 3;          // 0..7 (8 edges per load instruction)
    const int l = lane & 7;             // uint4 slot within the 128 B row
    const int waveGlobal = blockIdx.x * 4 + (threadIdx.x >> 6);
    const int totalWaves = gridDim.x * 4;
    const int nGroups = (E + (8 * U - 1)) / (8 * U);   // 32 edges per iteration

    for (int g = waveGlobal; g < nGroups; g += totalWaves) {
        const int e0 = g * (8 * U) + sub;   // edges e0 + 8u, u=0..U-1
        int s[U], t[U];
        bool v[U];
#pragma unroll
        for (int u = 0; u < U; ++u) {
            int e = e0 + u * 8;
            v[u] = (e < E);
            s[u] = v[u] ? idx[e] : 0;
            t[u] = v[u] ? idx[E + e] : 0;
        }
        // issue all 8 row-gather instructions before any arithmetic
        uint4 zq[U], xq[U];
#pragma unroll
        for (int u = 0; u < U; ++u) {
            zq[u] = ((const uint4*)(Zq + (size_t)s[u] * 128))[l];
            xq[u] = ((const uint4*)(Xq + (size_t)t[u] * 128))[l];
        }
        int acc[U];
#pragma unroll
        for (int u = 0; u < U; ++u) {
            int a = dot4x4_i8(zq[u], xq[u], 0);
            a += __shfl_xor(a, 1, 64);
            a += __shfl_xor(a, 2, 64);
            a += __shfl_xor(a, 4, 64);
            acc[u] = a;
        }
        if (l == 0) {
#pragma unroll
            for (int u = 0; u < U; ++u) {
                int e = e0 + u * 8;
                if (v[u]) out[e] = (float)acc[u] * zscales[s[u]] * xscales[t[u]] + b;
            }
        }
    }
}

extern "C" void kernel_launch(void* const* d_in, const int* in_sizes, int n_in,
                              void* d_out, int out_size, void* d_ws, size_t ws_size,
                              hipStream_t stream) {
    const float* x_source = (const float*)d_in[0];
    const float* x_target = (const float*)d_in[1];
    const int* edge_idx = (const int*)d_in[2];
    const float* W = (const float*)d_in[3];
    const float* b = (const float*)d_in[4];
    float* out = (float*)d_out;

    const int N = in_sizes[0] / D;           // 100000
    const int E = in_sizes[2] / 2;           // 2000000

    // workspace layout (256 B aligned blocks)
    size_t off = 0;
    auto take = [&](size_t bytes) {
        size_t o = off;
        off = (off + bytes + 255) & ~(size_t)255;
        return o;
    };
    signed char* Zq = (signed char*)((char*)d_ws + take((size_t)N * 128));
    signed char* Xq = (signed char*)((char*)d_ws + take((size_t)N * 128));
    float* zscales = (float*)((char*)d_ws + take((size_t)N * 4));
    float* xscales = (float*)((char*)d_ws + take((size_t)N * 4));
    unsigned short* Wth = (unsigned short*)((char*)d_ws + take((size_t)128 * 128 * 2));

    const int ngemm = (N + 63) / 64;
    const int nquant = (N + 63) / 64;

    wt_cast<<<64, 256, 0, stream>>>(W, Wth);
    fused_prep<<<ngemm + nquant, 256, 0, stream>>>(x_source, x_target, Wth,
                                                   Zq, zscales, Xq, xscales, N, ngemm);
    edge_score_q8<<<2048, 256, 0, stream>>>(Zq, Xq, zscales, xscales, edge_idx, b, out, E);
}

// Round 13
// 106.304 us; speedup vs baseline: 1.1896x; 1.1896x over previous
//
#include <hip/hip_runtime.h>
#include <hip/hip_bf16.h>

// Bilinear edge scoring:  out[e] = x_source[src[e]] @ W @ x_target[tgt[e]] + b
// Factored: Z = x_source @ W via f16 MFMA GEMM (fp32 accum), int8-quantized
//           per-row in the epilogue -> Zq + zscale; Xq = per-row int8 quant
//           of x_target; out[e] = zs[s]*xs[t]*idot(Zq[s], Xq[t]) + b.
// Edge phase (r11): 8 lanes/edge, 16 B/lane -> 8 row-segments per load
// instruction, U=4; 3.37 TB/s = 94% of the ~3.6 TB/s L2-miss-path wall.
// r12 lesson: fusing the streaming quant into the 48KB-LDS GEMM kernel cuts
// its occupancy (3 blocks/CU) and regresses -- keep roles in separate
// kernels. This round: W-cast folded into the quant kernel's grid (one
// fewer launch), quant at 2 rows/wave with float4 loads.
// Error: absmax 0.375 measured (threshold 0.69).

#define D 128
#define U 4      // edges per sub-group per wave-iteration (32 edges/wave-iter)

typedef _Float16 f16x8 __attribute__((ext_vector_type(8)));  // 4 VGPR
typedef float f32x4 __attribute__((ext_vector_type(4)));
typedef unsigned int uint;

__device__ __forceinline__ unsigned short f2h(float f) {
    _Float16 h = (_Float16)f;               // RNE
    return *(unsigned short*)&h;
}
__device__ __forceinline__ uint pack2h(float a, float b) {
    return (uint)f2h(a) | ((uint)f2h(b) << 16);
}

__device__ __forceinline__ int dot4x4_i8(uint4 a, uint4 b, int acc) {
#if __has_builtin(__builtin_amdgcn_sdot4)
    acc = __builtin_amdgcn_sdot4((int)a.x, (int)b.x, acc, false);
    acc = __builtin_amdgcn_sdot4((int)a.y, (int)b.y, acc, false);
    acc = __builtin_amdgcn_sdot4((int)a.z, (int)b.z, acc, false);
    acc = __builtin_amdgcn_sdot4((int)a.w, (int)b.w, acc, false);
#else
#pragma unroll
    for (int d = 0; d < 4; ++d) {
        uint av = (&a.x)[d], bv = (&b.x)[d];
#pragma unroll
        for (int k = 0; k < 4; ++k) {
            int az = (int)(signed char)((av >> (8 * k)) & 0xff);
            int bz = (int)(signed char)((bv >> (8 * k)) & 0xff);
            acc += az * bz;
        }
    }
#endif
    return acc;
}

// ---------------------------------------------------------------------------
// Quant + W-cast kernel (no LDS -> full occupancy).
// Blocks [0,nq): int8 per-row quant of x_target, 2 rows/wave, float4 loads
//   (lane: half=lane>>5 -> row, hl=lane&31 -> elems 4hl..4hl+3; 5x shfl_xor
//   max-reduce within the 32-lane half; packed uint store = 128 B/row).
// Blocks [nq,nq+8): Wth[n][k] = fp16(W[k][n]) (16384 elems, 8 per thread).
// Stream order guarantees Wth is complete before the GEMM launch runs.
// ---------------------------------------------------------------------------
__global__ __launch_bounds__(256) void quant8_x_wcast(const float* __restrict__ XT,
                                                      signed char* __restrict__ Xq,
                                                      float* __restrict__ xscales,
                                                      const float* __restrict__ W,
                                                      unsigned short* __restrict__ Wth,
                                                      int N, int nq) {
    if ((int)blockIdx.x >= nq) {
        // ---- W-cast role
        const int wb = (int)blockIdx.x - nq;            // 0..7
        const int base = wb * 2048 + threadIdx.x * 8;   // 8 elems/thread
#pragma unroll
        for (int j = 0; j < 8; ++j) {
            int idx = base + j;
            int k = idx >> 7, n = idx & 127;
            Wth[n * 128 + k] = f2h(W[idx]);
        }
        return;
    }
    // ---- quant role: 2 rows per wave
    const int w = threadIdx.x >> 6;
    const int lane = threadIdx.x & 63;
    const int half = lane >> 5;          // which of the wave's 2 rows
    const int hl = lane & 31;            // lane within the row
    const int row = ((int)blockIdx.x * 4 + w) * 2 + half;
    const bool valid = (row < N);

    float4 v = make_float4(0.f, 0.f, 0.f, 0.f);
    if (valid) v = ((const float4*)(XT + (size_t)row * D))[hl];
    float m = fmaxf(fmaxf(fabsf(v.x), fabsf(v.y)), fmaxf(fabsf(v.z), fabsf(v.w)));
#pragma unroll
    for (int o = 1; o < 32; o <<= 1) m = fmaxf(m, __shfl_xor(m, o, 64));
    if (valid) {
        const float inv = (m > 0.f) ? 127.0f / m : 0.f;
        int q0 = (int)rintf(v.x * inv);
        int q1 = (int)rintf(v.y * inv);
        int q2 = (int)rintf(v.z * inv);
        int q3 = (int)rintf(v.w * inv);
        uint pk = (uint)(q0 & 0xff) | ((uint)(q1 & 0xff) << 8) |
                  ((uint)(q2 & 0xff) << 16) | ((uint)(q3 & 0xff) << 24);
        *(uint*)((unsigned char*)Xq + (size_t)row * 128 + 4 * hl) = pk;
        if (hl == 0) xscales[row] = (m > 0.f) ? m * (1.0f / 127.0f) : 0.f;
    }
}

// ---------------------------------------------------------------------------
// Zq = int8_rowquant(X @ W) via mfma_f32_16x16x32_f16 (verified r8-r12).
// LDS XOR-swizzle byte^=(row&7)<<4 breaks the 256B-stride bank conflict.
// ---------------------------------------------------------------------------
__global__ __launch_bounds__(256) void gemm_xw_mfma_q8(const float* __restrict__ X,
                                                       const unsigned short* __restrict__ Wth,
                                                       signed char* __restrict__ Zq,
                                                       float* __restrict__ zscales, int N) {
    __shared__ unsigned short wls[128 * 128];
    __shared__ unsigned short xls[64 * 128];

    const int tid = threadIdx.x;
    const int block_row = blockIdx.x * 64;

#pragma unroll
    for (int j = 0; j < 8; ++j) {
        int c16 = j * 256 + tid;
        int row = c16 >> 4;
        int kb = (c16 & 15) << 4;
        uint4 v = ((const uint4*)Wth)[c16];
        *(uint4*)((char*)wls + row * 256 + (kb ^ ((row & 7) << 4))) = v;
    }
#pragma unroll
    for (int j = 0; j < 4; ++j) {
        int c16 = j * 256 + tid;
        int row = c16 >> 4;
        int kb = (c16 & 15) << 4;
        int grow = block_row + row;
        float4 f0 = make_float4(0.f, 0.f, 0.f, 0.f), f1 = f0;
        if (grow < N) {
            const float4* src = (const float4*)(X + (size_t)grow * D + (kb >> 1));
            f0 = src[0];
            f1 = src[1];
        }
        uint4 v;
        v.x = pack2h(f0.x, f0.y);
        v.y = pack2h(f0.z, f0.w);
        v.z = pack2h(f1.x, f1.y);
        v.w = pack2h(f1.z, f1.w);
        *(uint4*)((char*)xls + row * 256 + (kb ^ ((row & 7) << 4))) = v;
    }
    __syncthreads();

    const int lane = tid & 63;
    const int w = tid >> 6;
    const int lr = lane & 15;
    const int kg = lane >> 4;

    f32x4 acc[8];
#pragma unroll
    for (int nb = 0; nb < 8; ++nb) acc[nb] = (f32x4){0.f, 0.f, 0.f, 0.f};

    const int arow = w * 16 + lr;
    const int swz = (lr & 7) << 4;
#pragma unroll
    for (int ks = 0; ks < 4; ++ks) {
        int kbyte = ks * 64 + kg * 16;
        f16x8 a = *(const f16x8*)((const char*)xls + arow * 256 + (kbyte ^ swz));
#pragma unroll
        for (int nb = 0; nb < 8; ++nb) {
            int nrow = nb * 16 + lr;
            f16x8 b = *(const f16x8*)((const char*)wls + nrow * 256 + (kbyte ^ swz));
            acc[nb] = __builtin_amdgcn_mfma_f32_16x16x32_f16(a, b, acc[nb], 0, 0, 0);
        }
    }

    const int orow0 = block_row + w * 16 + kg * 4;
#pragma unroll
    for (int j = 0; j < 4; ++j) {
        float m = 0.f;
#pragma unroll
        for (int nb = 0; nb < 8; ++nb) m = fmaxf(m, fabsf(acc[nb][j]));
        m = fmaxf(m, __shfl_xor(m, 1, 64));
        m = fmaxf(m, __shfl_xor(m, 2, 64));
        m = fmaxf(m, __shfl_xor(m, 4, 64));
        m = fmaxf(m, __shfl_xor(m, 8, 64));   // max across the 16-lane lr group
        int grow = orow0 + j;
        if (grow < N) {
            float inv = (m > 0.f) ? 127.0f / m : 0.f;
#pragma unroll
            for (int nb = 0; nb < 8; ++nb) {
                int q = (int)rintf(acc[nb][j] * inv);
                Zq[(size_t)grow * 128 + nb * 16 + lr] = (signed char)q;
            }
            if (lr == 0) zscales[grow] = (m > 0.f) ? m * (1.0f / 127.0f) : 0.f;
        }
    }
}

// ---------------------------------------------------------------------------
// Edge pass (verified r11): 8 lanes/edge (lane l -> bytes 16l..16l+15),
// 8 rows = 8 x 128 B segments per load instruction, U=4 -> 32 edges/wave-iter,
// all 8 gather instrs issued before arithmetic. sdot4 dot, 3x shfl_xor
// reduce, scale-product epilogue on lane 0.
// ---------------------------------------------------------------------------
__global__ __launch_bounds__(256) void edge_score_q8(const signed char* __restrict__ Zq,
                                                     const signed char* __restrict__ Xq,
                                                     const float* __restrict__ zscales,
                                                     const float* __restrict__ xscales,
                                                     const int* __restrict__ idx,
                                                     const float* __restrict__ bptr,
                                                     float* __restrict__ out, int E) {
    const float b = bptr[0];
    const int lane = threadIdx.x & 63;
    const int sub = lane >> 3;          // 0..7 (8 edges per load instruction)
    const int l = lane & 7;             // uint4 slot within the 128 B row
    const int waveGlobal = blockIdx.x * 4 + (threadIdx.x >> 6);
    const int totalWaves = gridDim.x * 4;
    const int nGroups = (E + (8 * U - 1)) / (8 * U);   // 32 edges per iteration

    for (int g = waveGlobal; g < nGroups; g += totalWaves) {
        const int e0 = g * (8 * U) + sub;   // edges e0 + 8u, u=0..U-1
        int s[U], t[U];
        bool v[U];
#pragma unroll
        for (int u = 0; u < U; ++u) {
            int e = e0 + u * 8;
            v[u] = (e < E);
            s[u] = v[u] ? idx[e] : 0;
            t[u] = v[u] ? idx[E + e] : 0;
        }
        // issue all 8 row-gather instructions before any arithmetic
        uint4 zq[U], xq[U];
#pragma unroll
        for (int u = 0; u < U; ++u) {
            zq[u] = ((const uint4*)(Zq + (size_t)s[u] * 128))[l];
            xq[u] = ((const uint4*)(Xq + (size_t)t[u] * 128))[l];
        }
        int acc[U];
#pragma unroll
        for (int u = 0; u < U; ++u) {
            int a = dot4x4_i8(zq[u], xq[u], 0);
            a += __shfl_xor(a, 1, 64);
            a += __shfl_xor(a, 2, 64);
            a += __shfl_xor(a, 4, 64);
            acc[u] = a;
        }
        if (l == 0) {
#pragma unroll
            for (int u = 0; u < U; ++u) {
                int e = e0 + u * 8;
                if (v[u]) out[e] = (float)acc[u] * zscales[s[u]] * xscales[t[u]] + b;
            }
        }
    }
}

extern "C" void kernel_launch(void* const* d_in, const int* in_sizes, int n_in,
                              void* d_out, int out_size, void* d_ws, size_t ws_size,
                              hipStream_t stream) {
    const float* x_source = (const float*)d_in[0];
    const float* x_target = (const float*)d_in[1];
    const int* edge_idx = (const int*)d_in[2];
    const float* W = (const float*)d_in[3];
    const float* b = (const float*)d_in[4];
    float* out = (float*)d_out;

    const int N = in_sizes[0] / D;           // 100000
    const int E = in_sizes[2] / 2;           // 2000000

    // workspace layout (256 B aligned blocks)
    size_t off = 0;
    auto take = [&](size_t bytes) {
        size_t o = off;
        off = (off + bytes + 255) & ~(size_t)255;
        return o;
    };
    signed char* Zq = (signed char*)((char*)d_ws + take((size_t)N * 128));
    signed char* Xq = (signed char*)((char*)d_ws + take((size_t)N * 128));
    float* zscales = (float*)((char*)d_ws + take((size_t)N * 4));
    float* xscales = (float*)((char*)d_ws + take((size_t)N * 4));
    unsigned short* Wth = (unsigned short*)((char*)d_ws + take((size_t)128 * 128 * 2));

    const int nq = (N + 7) / 8;              // 8 rows per block (4 waves x 2)

    quant8_x_wcast<<<nq + 8, 256, 0, stream>>>(x_target, Xq, xscales, W, Wth, N, nq);
    gemm_xw_mfma_q8<<<(N + 63) / 64, 256, 0, stream>>>(x_source, Wth, Zq, zscales, N);
    edge_score_q8<<<2048, 256, 0, stream>>>(Zq, Xq, zscales, xscales, edge_idx, b, out, E);
}